// Round 12
// baseline (242.908 us; speedup 1.0000x reference)
//
#include <hip/hip_runtime.h>
#include <hip/hip_bf16.h>
#include <cstdint>
#include <cmath>

#define NROWS 4096
#define DIM   2048
#define CNUM  128
#define MARGIN_F 0.3f
#define TOPK 12
#define MAXM 256
#define GBK 32          // K-tile (f16 elements), double-buffered
#define CAP 160         // topk candidate buffer per wave
#define T64 64          // GEMM tile edge

// fallback-path tiling
#define BM 64
#define BN 64
#define BK 16
#define SLICES 8
#define COLS_PER_SLICE (NROWS / SLICES)

typedef _Float16 f16x8 __attribute__((ext_vector_type(8)));
typedef float    f32x4 __attribute__((ext_vector_type(4)));

// async global->LDS, 16 B per lane; lds dest = wave-uniform base + lane*16
#define GLD_LDS16(g, l)                                                        \
    __builtin_amdgcn_global_load_lds(                                          \
        (const __attribute__((address_space(1))) uint32_t*)(g),                \
        (__attribute__((address_space(3))) uint32_t*)(l), 16, 0, 0)

__device__ __forceinline__ uint32_t rnd_u32(uint32_t row, uint32_t k) {
    uint64_t x = ((uint64_t)row << 32) ^ (0x9E3779B97F4A7C15ULL * (uint64_t)(k + 1u));
    x ^= x >> 33; x *= 0xff51afd7ed558ccdULL;
    x ^= x >> 33; x *= 0xc4ceb9fe1a85ec53ULL;
    x ^= x >> 33;
    return (uint32_t)x;
}

// ---------- fast path: FUSED setup — prep (convert+rowsq) / predcls / classlist ----
__global__ void setup_kernel(const float* __restrict__ X, _Float16* __restrict__ Xh,
                             float* __restrict__ sq,
                             const float* __restrict__ P, int* __restrict__ cls,
                             const int* __restrict__ tgt,
                             int* __restrict__ cnt, int* __restrict__ members) {
    int b = blockIdx.x, tid = threadIdx.x;
    int wave = tid >> 6, lane = tid & 63;

    if (b < NROWS) {
        __shared__ float ws[4];
        int row = b;
        const float4* xp = (const float4*)(X + (size_t)row * DIM);
        float4 a = xp[tid * 2], v2 = xp[tid * 2 + 1];
        float s = a.x * a.x + a.y * a.y + a.z * a.z + a.w * a.w
                + v2.x * v2.x + v2.y * v2.y + v2.z * v2.z + v2.w * v2.w;
        _Float16 h[8] = { (_Float16)a.x, (_Float16)a.y, (_Float16)a.z, (_Float16)a.w,
                          (_Float16)v2.x, (_Float16)v2.y, (_Float16)v2.z, (_Float16)v2.w };
        ((uint4*)(Xh + (size_t)row * DIM))[tid] = *(uint4*)h;
        for (int off = 32; off; off >>= 1) s += __shfl_xor(s, off, 64);
        if (lane == 0) ws[wave] = s;
        __syncthreads();
        if (tid == 0) sq[row] = ws[0] + ws[1] + ws[2] + ws[3];
    } else if (b < NROWS + NROWS / 4) {
        int row = (b - NROWS) * 4 + wave;
        const float* p = P + (size_t)row * CNUM;
        float v0 = p[lane]; int i0 = lane;
        float v1 = p[lane + 64];
        if (v1 > v0) { v0 = v1; i0 = lane + 64; }
        for (int off = 1; off < 64; off <<= 1) {
            float ov = __shfl_xor(v0, off, 64);
            int   oi = __shfl_xor(i0, off, 64);
            if (ov > v0 || (ov == v0 && oi < i0)) { v0 = ov; i0 = oi; }
        }
        if (lane == 0) cls[row] = i0;
    } else {
        int c = (b - NROWS - NROWS / 4) * 4 + wave;
        if (c >= CNUM) return;
        int k = 0;
        for (int base = 0; base < NROWS; base += 64) {
            int i = base + lane;
            bool m = (tgt[i] == c);
            unsigned long long mask = __ballot(m);
            if (m) {
                int pos = k + __popcll(mask & ((1ull << lane) - 1ull));
                if (pos < MAXM) members[c * MAXM + pos] = i;
            }
            k += __popcll(mask);
        }
        if (lane == 0) cnt[c] = (k < MAXM) ? k : MAXM;
    }
}

// ---------- fallback: row sum of squares ----------
__global__ void rowsq_kernel(const float* __restrict__ X, float* __restrict__ sq) {
    int wave = (blockIdx.x * blockDim.x + threadIdx.x) >> 6;
    int lane = threadIdx.x & 63;
    if (wave >= NROWS) return;
    const float4* xp = (const float4*)(X + (size_t)wave * DIM);
    float s = 0.f;
    for (int k = lane; k < DIM / 4; k += 64) {
        float4 v = xp[k];
        s += v.x * v.x + v.y * v.y + v.z * v.z + v.w * v.w;
    }
    for (int off = 32; off; off >>= 1) s += __shfl_xor(s, off, 64);
    if (lane == 0) sq[wave] = s;
}

// ---------- fallback: predcls ----------
__global__ void predcls_kernel(const float* __restrict__ P, int* __restrict__ cls) {
    int row = (blockIdx.x * blockDim.x + threadIdx.x) >> 6;
    int lane = threadIdx.x & 63;
    if (row >= NROWS) return;
    const float* p = P + (size_t)row * CNUM;
    float v0 = p[lane]; int i0 = lane;
    float v1 = p[lane + 64];
    if (v1 > v0) { v0 = v1; i0 = lane + 64; }
    for (int off = 1; off < 64; off <<= 1) {
        float ov = __shfl_xor(v0, off, 64);
        int   oi = __shfl_xor(i0, off, 64);
        if (ov > v0 || (ov == v0 && oi < i0)) { v0 = ov; i0 = oi; }
    }
    if (lane == 0) cls[row] = i0;
}

// ---------- fallback: classlist ----------
__global__ void classlist_kernel(const int* __restrict__ tgt,
                                 int* __restrict__ cnt, int* __restrict__ members) {
    int c = (blockIdx.x * blockDim.x + threadIdx.x) >> 6;
    int lane = threadIdx.x & 63;
    if (c >= CNUM) return;
    int k = 0;
    for (int base = 0; base < NROWS; base += 64) {
        int i = base + lane;
        bool m = (tgt[i] == c);
        unsigned long long mask = __ballot(m);
        if (m) {
            int pos = k + __popcll(mask & ((1ull << lane) - 1ull));
            if (pos < MAXM) members[c * MAXM + pos] = i;
        }
        k += __popcll(mask);
    }
    if (lane == 0) cnt[c] = (k < MAXM) ? k : MAXM;
}

// ---------- fast path: f16 MFMA Gram, 64x64 tiles for occupancy ----------
// 2080 upper-triangle 64x64 tiles = 8.1 blocks/CU grid; LDS ~21 KB -> 6-7
// blocks/CU capacity -> ~24+ waves/CU. R11's 128-tile ran at 29% combined
// pipe utilization with only 8 waves/CU (528-block grid): latency-bound.
// 4 waves as 2x2 of 32x32 quadrants; BK=32 double-buffered; same swizzle.
__launch_bounds__(256, 6)
__global__ void mfma_dist_kernel(const _Float16* __restrict__ Xh,
                                 const float* __restrict__ sq, const int* __restrict__ tgt,
                                 float* __restrict__ dist) {
    __shared__ _Float16 Ah[2][T64 * GBK];   // 2 x 4 KB
    __shared__ _Float16 Bh[2][T64 * GBK];   // 2 x 4 KB
    __shared__ float    trb[4][16 * 17];    // 4.25 KB
    __shared__ float    sqA[T64], sqB[T64];
    __shared__ int      tgA[T64], tgB[T64];

    int b = blockIdx.x;
    int br = 0, S = 0;
    while (b >= S + (64 - br)) { S += 64 - br; br++; }
    int bc = br + (b - S);

    int r0 = br * T64, c0 = bc * T64;
    int tid = threadIdx.x;
    int wave = tid >> 6, lane = tid & 63;
    int wr = wave >> 1, wc = wave & 1;

    if (tid < T64) { sqA[tid] = sq[r0 + tid]; tgA[tid] = tgt[r0 + tid]; }
    else if (tid < 2 * T64) { int t = tid - T64; sqB[t] = sq[c0 + t]; tgB[t] = tgt[c0 + t]; }

    f32x4 acc[2][2];
#pragma unroll
    for (int i = 0; i < 2; i++)
#pragma unroll
        for (int j = 0; j < 2; j++) acc[i][j] = (f32x4)0.f;

    // staging: wave w loads A rows [w*16, w*16+16) and B rows likewise (1 KB each)
    int rl = wave * 16 + (lane >> 2);                 // local row 0..63
    int slot = lane & 3;                              // dest 16B slot in row
    int csrc = (slot - ((rl >> 1) & 3)) & 3;          // swizzled source chunk
    const _Float16* gA = Xh + (size_t)(r0 + rl) * DIM + csrc * 8;
    const _Float16* gB = Xh + (size_t)(c0 + rl) * DIM + csrc * 8;
    int ldsOff = wave * 16 * GBK;                     // wave-uniform base

    auto stage = [&](int buf, int kOff) {
        GLD_LDS16(gA + kOff, &Ah[buf][ldsOff]);
        GLD_LDS16(gB + kOff, &Bh[buf][ldsOff]);
    };

    stage(0, 0);
    int fr = lane & 15, fq = lane >> 4;

    for (int it = 0; it < DIM / GBK; it++) {          // 64 iterations
        int cur = it & 1;
        __syncthreads();                              // prefetch drained; buffer safe
        if (it + 1 < DIM / GBK) stage(cur ^ 1, (it + 1) * GBK);
        f16x8 af[2], bf[2];
#pragma unroll
        for (int i = 0; i < 2; i++) {
            int row = wr * 32 + i * 16 + fr;
            int sl = (fq + ((row >> 1) & 3)) & 3;
            af[i] = *(const f16x8*)&Ah[cur][row * GBK + sl * 8];
        }
#pragma unroll
        for (int j = 0; j < 2; j++) {
            int col = wc * 32 + j * 16 + fr;
            int sl = (fq + ((col >> 1) & 3)) & 3;
            bf[j] = *(const f16x8*)&Bh[cur][col * GBK + sl * 8];
        }
#pragma unroll
        for (int i = 0; i < 2; i++)
#pragma unroll
            for (int j = 0; j < 2; j++)
                acc[i][j] = __builtin_amdgcn_mfma_f32_16x16x32_f16(af[i], bf[j], acc[i][j], 0, 0, 0);
    }

    // epilogue: d2 = sqA+sqB-2*dot, mask positives; NT direct + NT transposed mirror
    float* tb = trb[wave];
#pragma unroll
    for (int i = 0; i < 2; i++) {
#pragma unroll
        for (int j = 0; j < 2; j++) {
            int lcol = wc * 32 + j * 16 + fr;
            float d[4];
#pragma unroll
            for (int r = 0; r < 4; r++) {
                int lrow = wr * 32 + i * 16 + fq * 4 + r;
                float v = sqA[lrow] + sqB[lcol] - 2.f * acc[i][j][r];
                if (tgA[lrow] == tgB[lcol]) v = INFINITY;
                d[r] = v;
                __builtin_nontemporal_store(v, &dist[(size_t)(r0 + lrow) * NROWS + (c0 + lcol)]);
            }
            if (br != bc) {
#pragma unroll
                for (int r = 0; r < 4; r++) tb[fr * 17 + fq * 4 + r] = d[r];
#pragma unroll
                for (int r = 0; r < 4; r++) {
                    float v = tb[(fq * 4 + r) * 17 + fr];
                    int grow = c0 + wc * 32 + j * 16 + fq * 4 + r;
                    int gcol = r0 + wr * 32 + i * 16 + fr;
                    __builtin_nontemporal_store(v, &dist[(size_t)grow * NROWS + gcol]);
                }
            }
        }
    }
}

// ---------- fast path: per-row top-12 via pivot filter + ballot compaction (R8) ----
__launch_bounds__(256)
__global__ void topk_kernel(const float* __restrict__ dist,
                            float* __restrict__ top_v, int* __restrict__ top_i) {
    __shared__ float cbv[4][CAP];
    __shared__ int   cbi[4][CAP];
    int wave = threadIdx.x >> 6, lane = threadIdx.x & 63;
    int row = blockIdx.x * 4 + wave;
    const f32x4* d = (const f32x4*)(dist + (size_t)row * NROWS);

    f32x4 v[16];
#pragma unroll
    for (int t = 0; t < 16; t++) v[t] = __builtin_nontemporal_load(&d[t * 64 + lane]);

    float lmin = INFINITY, lmax = -INFINITY, lsum = 0.f;
    int lcnt = 0;
#pragma unroll
    for (int t = 0; t < 16; t++) {
#pragma unroll
        for (int c = 0; c < 4; c++) {
            float x = v[t][c];
            bool fin = x < INFINITY;
            lmin = fminf(lmin, x);
            lmax = fmaxf(lmax, fin ? x : -INFINITY);
            lsum += fin ? x : 0.f;
            lcnt += fin ? 1 : 0;
        }
    }
    for (int off = 32; off; off >>= 1) {
        lmin = fminf(lmin, __shfl_xor(lmin, off, 64));
        lmax = fmaxf(lmax, __shfl_xor(lmax, off, 64));
        lsum += __shfl_xor(lsum, off, 64);
        lcnt += __shfl_xor(lcnt, off, 64);
    }
    float mu = lsum / (float)(lcnt > 0 ? lcnt : 1);

    float lo = lmin, hi = lmax + 1.0f;
    float tau = lmin + 0.3f * (mu - lmin);
    if (!(tau > lo && tau < hi)) tau = 0.5f * (lo + hi);
    for (int it = 0; it < 32; it++) {
        int lc = 0;
#pragma unroll
        for (int t = 0; t < 16; t++) {
            lc += (v[t][0] < tau) + (v[t][1] < tau) + (v[t][2] < tau) + (v[t][3] < tau);
        }
        for (int off = 32; off; off >>= 1) lc += __shfl_xor(lc, off, 64);
        if (lc >= TOPK && lc <= CAP) break;
        if (lc < TOPK) lo = tau; else hi = tau;
        tau = 0.5f * (lo + hi);
    }

    int cnt = 0;
#pragma unroll
    for (int t = 0; t < 16; t++) {
#pragma unroll
        for (int c = 0; c < 4; c++) {
            float x = v[t][c];
            bool p = x < tau;
            unsigned long long mk = __ballot(p);
            if (p) {
                int pos = cnt + __popcll(mk & ((1ull << lane) - 1ull));
                if (pos < CAP) {
                    cbv[wave][pos] = x;
                    cbi[wave][pos] = (t * 64 + lane) * 4 + c;
                }
            }
            cnt += __popcll(mk);
        }
    }
    if (cnt > CAP) cnt = CAP;

    float mv[3]; int mi[3];
#pragma unroll
    for (int r = 0; r < 3; r++) {
        int p = r * 64 + lane;
        bool ok = p < cnt;
        mv[r] = ok ? cbv[wave][p] : INFINITY;
        mi[r] = ok ? cbi[wave][p] : 0x7FFFFFFF;
    }

    for (int t = 0; t < TOPK; t++) {
        float bv = mv[0]; int bi = mi[0];
        if (mv[1] < bv || (mv[1] == bv && mi[1] < bi)) { bv = mv[1]; bi = mi[1]; }
        if (mv[2] < bv || (mv[2] == bv && mi[2] < bi)) { bv = mv[2]; bi = mi[2]; }
        for (int off = 32; off; off >>= 1) {
            float ov = __shfl_xor(bv, off, 64);
            int   oi = __shfl_xor(bi, off, 64);
            if (ov < bv || (ov == bv && oi < bi)) { bv = ov; bi = oi; }
        }
        if (lane == 0) {
            top_v[(size_t)row * TOPK + t] = bv;
            int si = (bi >= 0 && bi < NROWS) ? bi : 0;
            top_i[(size_t)row * TOPK + t] = si;
        }
#pragma unroll
        for (int r = 0; r < 3; r++)
            if (mi[r] == bi) { mv[r] = INFINITY; mi[r] = 0x7FFFFFFF; }
    }
}

// ---------- fallback path (proven R1): fused fp32 GEMM + per-row top-12 ----------
__launch_bounds__(256)
__global__ void dist_topk_kernel(const float* __restrict__ X, const float* __restrict__ sq,
                                 const int* __restrict__ tgt,
                                 float* __restrict__ part_v, int* __restrict__ part_i) {
    __shared__ float As[BK][BM];
    __shared__ float Bs[BK][BN];
    __shared__ float Cs[BM][BN + 1];
    __shared__ float sqA[BM], sqB[BN];
    __shared__ int   tgA[BM], tgB[BN];

    int rowBase = blockIdx.x * BM;
    int slice = blockIdx.y;
    int tid = threadIdx.x;
    int tx = tid & 15, ty = tid >> 4;

    if (tid < BM) { sqA[tid] = sq[rowBase + tid]; tgA[tid] = tgt[rowBase + tid]; }

    float lv[TOPK]; int li[TOPK];
#pragma unroll
    for (int k = 0; k < TOPK; k++) { lv[k] = INFINITY; li[k] = -1; }

    for (int jt = 0; jt < COLS_PER_SLICE / BN; jt++) {
        int colBase = slice * COLS_PER_SLICE + jt * BN;
        __syncthreads();
        if (tid < BN) { sqB[tid] = sq[colBase + tid]; tgB[tid] = tgt[colBase + tid]; }

        float acc[4][4] = {};
        for (int kb = 0; kb < DIM; kb += BK) {
            int r  = tid >> 2;
            int kk = (tid & 3) * 4;
            float4 va = *(const float4*)(X + (size_t)(rowBase + r) * DIM + kb + kk);
            As[kk + 0][r] = va.x; As[kk + 1][r] = va.y; As[kk + 2][r] = va.z; As[kk + 3][r] = va.w;
            float4 vb = *(const float4*)(X + (size_t)(colBase + r) * DIM + kb + kk);
            Bs[kk + 0][r] = vb.x; Bs[kk + 1][r] = vb.y; Bs[kk + 2][r] = vb.z; Bs[kk + 3][r] = vb.w;
            __syncthreads();
#pragma unroll
            for (int k = 0; k < BK; k++) {
                float a[4], b2[4];
                *(float4*)a = *(const float4*)&As[k][ty * 4];
                *(float4*)b2 = *(const float4*)&Bs[k][tx * 4];
#pragma unroll
                for (int i2 = 0; i2 < 4; i2++)
#pragma unroll
                    for (int j2 = 0; j2 < 4; j2++)
                        acc[i2][j2] += a[i2] * b2[j2];
            }
            __syncthreads();
        }
#pragma unroll
        for (int i2 = 0; i2 < 4; i2++) {
            int r = ty * 4 + i2;
#pragma unroll
            for (int j2 = 0; j2 < 4; j2++) {
                int c = tx * 4 + j2;
                float d2 = sqA[r] + sqB[c] - 2.f * acc[i2][j2];
                if (tgA[r] == tgB[c]) d2 = INFINITY;
                Cs[r][c] = d2;
            }
        }
        __syncthreads();
        if (tid < BM) {
            int r = tid;
            for (int c = 0; c < BN; c++) {
                float v = Cs[r][c];
                if (v < lv[TOPK - 1]) {
                    float nv = v; int ni = colBase + c;
#pragma unroll
                    for (int p = 0; p < TOPK; p++) {
                        if (nv < lv[p]) {
                            float tv = lv[p]; int ti = li[p];
                            lv[p] = nv; li[p] = ni;
                            nv = tv; ni = ti;
                        }
                    }
                }
            }
        }
    }
    if (tid < BM) {
        int r = tid;
#pragma unroll
        for (int k = 0; k < TOPK; k++) {
            size_t o = ((size_t)(rowBase + r) * SLICES + slice) * TOPK + k;
            part_v[o] = lv[k];
            part_i[o] = li[k];
        }
    }
}

__global__ void topk_merge_kernel(const float* __restrict__ part_v, const int* __restrict__ part_i,
                                  float* __restrict__ top_v, int* __restrict__ top_i) {
    int row = blockIdx.x * blockDim.x + threadIdx.x;
    if (row >= NROWS) return;
    float lv[TOPK]; int li[TOPK];
#pragma unroll
    for (int k = 0; k < TOPK; k++) { lv[k] = INFINITY; li[k] = -1; }
    for (int s = 0; s < SLICES; s++) {
        for (int k = 0; k < TOPK; k++) {
            size_t o = ((size_t)row * SLICES + s) * TOPK + k;
            float v = part_v[o];
            if (!(v < lv[TOPK - 1])) break;
            int idx = part_i[o];
            float nv = v; int ni = idx;
#pragma unroll
            for (int p = 0; p < TOPK; p++) {
                if (nv < lv[p]) {
                    float tv = lv[p]; int ti = li[p];
                    lv[p] = nv; li[p] = ni;
                    nv = tv; ni = ti;
                }
            }
        }
    }
#pragma unroll
    for (int k = 0; k < TOPK; k++) {
        top_v[(size_t)row * TOPK + k] = lv[k];
        top_i[(size_t)row * TOPK + k] = li[k];
    }
}

// ---------- kernel 5: per-row triplet logic (one wave per row; f16 dots) ----------
__global__ void rowlogic_kernel(const _Float16* __restrict__ Xh, const float* __restrict__ sq,
                                const float* __restrict__ prob, const float* __restrict__ thr_p,
                                const int* __restrict__ tgt, const int* __restrict__ pred_cls,
                                const int* __restrict__ class_cnt, const int* __restrict__ class_mem,
                                const float* __restrict__ top_v, const int* __restrict__ top_i,
                                float* __restrict__ row_loss, int* __restrict__ row_corr) {
    int i = (blockIdx.x * blockDim.x + threadIdx.x) >> 6;
    int lane = threadIdx.x & 63;
    if (i >= NROWS) return;
    float thr = *thr_p;

    int c = tgt[i];
    int cc = class_cnt[c];
    const int* mem = class_mem + c * MAXM;

    int pos_i = 0;
    for (int k = 0; k < cc; k++) { if (mem[k] == i) { pos_i = k; break; } }

    int rp = 0;
    if (cc > 1) {
        uint32_t r = rnd_u32((uint32_t)i, 0x9111u) % (uint32_t)(cc - 1);
        if ((int)r >= pos_i) r++;
        rp = mem[r];
    }

    int hn = top_i[(size_t)i * TOPK + 0];
    float an0 = sqrtf(fmaxf(top_v[(size_t)i * TOPK + 0], 1e-12f));
    bool p_neg = prob[hn] >= thr;
    bool is_FN = (pred_cls[hn] == c);

    int sel = 11;
    for (int k = 1; k <= 11; k++) {
        int cd = top_i[(size_t)i * TOPK + k];
        if (prob[cd] >= thr) { sel = k; break; }
    }
    float anB = sqrtf(fmaxf(top_v[(size_t)i * TOPK + sel], 1e-12f));

    int first_valid = -1, last_draw = 0;
    for (int k = 0; k < 6; k++) {
        uint32_t r = rnd_u32((uint32_t)i, 0xD000u + (uint32_t)k) % (uint32_t)(cc > 0 ? cc : 1);
        int dk = mem[r];
        last_draw = dk;
        if (first_valid < 0 && dk != i && prob[dk] >= thr) first_valid = dk;
    }
    int rp_new = (first_valid >= 0) ? first_valid : last_draw;
    bool p_pos = prob[rp] >= thr;

    const f16x8* xi = (const f16x8*)(Xh + (size_t)i * DIM);
    const f16x8* xr = (const f16x8*)(Xh + (size_t)rp * DIM);
    const f16x8* xn = (const f16x8*)(Xh + (size_t)rp_new * DIM);
    float s1 = 0.f, s2 = 0.f;
    for (int k = lane; k < DIM / 8; k += 64) {
        f16x8 a = xi[k], b = xr[k], d = xn[k];
#pragma unroll
        for (int e = 0; e < 8; e++) {
            float ax = (float)a[e];
            s1 += ax * (float)b[e];
            s2 += ax * (float)d[e];
        }
    }
    for (int off = 32; off; off >>= 1) {
        s1 += __shfl_xor(s1, off, 64);
        s2 += __shfl_xor(s2, off, 64);
    }
    if (lane == 0) {
        float ap0 = sqrtf(fmaxf(sq[i] + sq[rp]     - 2.f * s1, 1e-12f));
        float apC = sqrtf(fmaxf(sq[i] + sq[rp_new] - 2.f * s2, 1e-12f));
        float apB = (ap0 + an0) * 0.5f;
        float anC = (ap0 + an0) * 0.5f;
        bool useB = p_pos && !p_neg && is_FN;
        bool useC = (!p_pos && p_neg) || (!p_pos && !p_neg && !is_FN);
        bool inverse = !p_pos && !p_neg && is_FN;
        float ap = useB ? apB : (useC ? apC : ap0);
        float an = useB ? anB : (useC ? anC : an0);
        float pl = inverse ? fmaxf(an - ap + MARGIN_F, 0.f)
                           : fmaxf(ap - an + MARGIN_F, 0.f);
        bool conf = prob[i] >= thr;
        row_loss[i] = conf ? pl : 0.f;
        row_corr[i] = (conf && (an >= ap)) ? 1 : 0;
    }
}

// fallback rowlogic on fp32 X
__global__ void rowlogic_f32_kernel(const float* __restrict__ X, const float* __restrict__ sq,
                                    const float* __restrict__ prob, const float* __restrict__ thr_p,
                                    const int* __restrict__ tgt, const int* __restrict__ pred_cls,
                                    const int* __restrict__ class_cnt, const int* __restrict__ class_mem,
                                    const float* __restrict__ top_v, const int* __restrict__ top_i,
                                    float* __restrict__ row_loss, int* __restrict__ row_corr) {
    int i = (blockIdx.x * blockDim.x + threadIdx.x) >> 6;
    int lane = threadIdx.x & 63;
    if (i >= NROWS) return;
    float thr = *thr_p;

    int c = tgt[i];
    int cc = class_cnt[c];
    const int* mem = class_mem + c * MAXM;

    int pos_i = 0;
    for (int k = 0; k < cc; k++) { if (mem[k] == i) { pos_i = k; break; } }

    int rp = 0;
    if (cc > 1) {
        uint32_t r = rnd_u32((uint32_t)i, 0x9111u) % (uint32_t)(cc - 1);
        if ((int)r >= pos_i) r++;
        rp = mem[r];
    }

    int hn = top_i[(size_t)i * TOPK + 0];
    float an0 = sqrtf(fmaxf(top_v[(size_t)i * TOPK + 0], 1e-12f));
    bool p_neg = prob[hn] >= thr;
    bool is_FN = (pred_cls[hn] == c);

    int sel = 11;
    for (int k = 1; k <= 11; k++) {
        int cd = top_i[(size_t)i * TOPK + k];
        if (prob[cd] >= thr) { sel = k; break; }
    }
    float anB = sqrtf(fmaxf(top_v[(size_t)i * TOPK + sel], 1e-12f));

    int first_valid = -1, last_draw = 0;
    for (int k = 0; k < 6; k++) {
        uint32_t r = rnd_u32((uint32_t)i, 0xD000u + (uint32_t)k) % (uint32_t)(cc > 0 ? cc : 1);
        int dk = mem[r];
        last_draw = dk;
        if (first_valid < 0 && dk != i && prob[dk] >= thr) first_valid = dk;
    }
    int rp_new = (first_valid >= 0) ? first_valid : last_draw;
    bool p_pos = prob[rp] >= thr;

    const float4* xi = (const float4*)(X + (size_t)i * DIM);
    const float4* xr = (const float4*)(X + (size_t)rp * DIM);
    const float4* xn = (const float4*)(X + (size_t)rp_new * DIM);
    float s1 = 0.f, s2 = 0.f;
    for (int k = lane; k < DIM / 4; k += 64) {
        float4 a = xi[k], b = xr[k], d = xn[k];
        s1 += a.x * b.x + a.y * b.y + a.z * b.z + a.w * b.w;
        s2 += a.x * d.x + a.y * d.y + a.z * d.z + a.w * d.w;
    }
    for (int off = 32; off; off >>= 1) {
        s1 += __shfl_xor(s1, off, 64);
        s2 += __shfl_xor(s2, off, 64);
    }
    if (lane == 0) {
        float ap0 = sqrtf(fmaxf(sq[i] + sq[rp]     - 2.f * s1, 1e-12f));
        float apC = sqrtf(fmaxf(sq[i] + sq[rp_new] - 2.f * s2, 1e-12f));
        float apB = (ap0 + an0) * 0.5f;
        float anC = (ap0 + an0) * 0.5f;
        bool useB = p_pos && !p_neg && is_FN;
        bool useC = (!p_pos && p_neg) || (!p_pos && !p_neg && !is_FN);
        bool inverse = !p_pos && !p_neg && is_FN;
        float ap = useB ? apB : (useC ? apC : ap0);
        float an = useB ? anB : (useC ? anC : an0);
        float pl = inverse ? fmaxf(an - ap + MARGIN_F, 0.f)
                           : fmaxf(ap - an + MARGIN_F, 0.f);
        bool conf = prob[i] >= thr;
        row_loss[i] = conf ? pl : 0.f;
        row_corr[i] = (conf && (an >= ap)) ? 1 : 0;
    }
}

// ---------- kernel 6: final reduction ----------
__global__ void reduce_kernel(const float* __restrict__ row_loss, const int* __restrict__ row_corr,
                              const float* __restrict__ prob, const float* __restrict__ thr_p,
                              float* __restrict__ out) {
    __shared__ float sl[256];
    __shared__ int   sc[256];
    __shared__ int   sn[256];
    float thr = *thr_p;
    int tid = threadIdx.x;
    float l = 0.f; int corr = 0, cnt = 0;
    for (int i = tid; i < NROWS; i += 256) {
        l += row_loss[i];
        corr += row_corr[i];
        cnt += (prob[i] >= thr) ? 1 : 0;
    }
    sl[tid] = l; sc[tid] = corr; sn[tid] = cnt;
    __syncthreads();
    for (int off = 128; off; off >>= 1) {
        if (tid < off) {
            sl[tid] += sl[tid + off];
            sc[tid] += sc[tid + off];
            sn[tid] += sn[tid + off];
        }
        __syncthreads();
    }
    if (tid == 0) {
        int cn = sn[0];
        float loss = (cn > 0) ? (sl[0] / (float)(cn > 1 ? cn : 1)) : 0.f;
        out[0] = loss;
        out[1] = (float)sc[0];
        out[2] = (float)cn;
    }
}

extern "C" void kernel_launch(void* const* d_in, const int* in_sizes, int n_in,
                              void* d_out, int out_size, void* d_ws, size_t ws_size,
                              hipStream_t stream) {
    const float* X    = (const float*)d_in[0];
    const float* P    = (const float*)d_in[1];
    const int*   tgt  = (const int*)d_in[2];
    const float* prob = (const float*)d_in[4];
    const float* thr  = (const float*)d_in[5];
    float* out = (float*)d_out;

    char* w = (char*)d_ws;
    auto alloc = [&](size_t bytes) {
        char* p = w;
        w += (bytes + 255) & ~(size_t)255;
        return p;
    };
    float* sq        = (float*)alloc(NROWS * sizeof(float));
    int*   pred_cls  = (int*)  alloc(NROWS * sizeof(int));
    int*   class_cnt = (int*)  alloc(CNUM * sizeof(int));
    int*   class_mem = (int*)  alloc((size_t)CNUM * MAXM * sizeof(int));
    float* top_v     = (float*)alloc((size_t)NROWS * TOPK * sizeof(float));
    int*   top_i     = (int*)  alloc((size_t)NROWS * TOPK * sizeof(int));
    float* row_loss  = (float*)alloc(NROWS * sizeof(float));
    int*   row_corr  = (int*)  alloc(NROWS * sizeof(int));
    char*  var_base  = w;

    // fast path: Xh (16.8 MB) + fp32 dist (64 MB)
    size_t fast_need = (size_t)NROWS * DIM * 2 + (size_t)NROWS * NROWS * 4 + (1 << 20);
    bool fast = ((size_t)(var_base - (char*)d_ws) + fast_need) <= ws_size;

    if (fast) {
        _Float16* Xh   = (_Float16*)alloc((size_t)NROWS * DIM * 2);
        float*    dist = (float*)alloc((size_t)NROWS * NROWS * 4);
        setup_kernel<<<NROWS + NROWS / 4 + CNUM / 4, 256, 0, stream>>>(
            X, Xh, sq, P, pred_cls, tgt, class_cnt, class_mem);
        mfma_dist_kernel<<<(64 * 65) / 2, 256, 0, stream>>>(Xh, sq, tgt, dist);
        topk_kernel<<<NROWS / 4, 256, 0, stream>>>(dist, top_v, top_i);
        rowlogic_kernel<<<NROWS / 4, 256, 0, stream>>>(Xh, sq, prob, thr, tgt, pred_cls,
                                                       class_cnt, class_mem, top_v, top_i,
                                                       row_loss, row_corr);
    } else {
        rowsq_kernel<<<NROWS / 4, 256, 0, stream>>>(X, sq);
        predcls_kernel<<<NROWS / 4, 256, 0, stream>>>(P, pred_cls);
        classlist_kernel<<<CNUM / 4, 256, 0, stream>>>(tgt, class_cnt, class_mem);
        float* part_v = (float*)alloc((size_t)NROWS * SLICES * TOPK * sizeof(float));
        int*   part_i = (int*)  alloc((size_t)NROWS * SLICES * TOPK * sizeof(int));
        dist_topk_kernel<<<dim3(NROWS / BM, SLICES), 256, 0, stream>>>(X, sq, tgt, part_v, part_i);
        topk_merge_kernel<<<NROWS / 256, 256, 0, stream>>>(part_v, part_i, top_v, top_i);
        rowlogic_f32_kernel<<<NROWS / 4, 256, 0, stream>>>(X, sq, prob, thr, tgt, pred_cls,
                                                           class_cnt, class_mem, top_v, top_i,
                                                           row_loss, row_corr);
    }

    reduce_kernel<<<1, 256, 0, stream>>>(row_loss, row_corr, prob, thr, out);
}

// Round 13
// 214.371 us; speedup vs baseline: 1.1331x; 1.1331x over previous
//
#include <hip/hip_runtime.h>
#include <hip/hip_bf16.h>
#include <cstdint>
#include <cmath>

#define NROWS 4096
#define DIM   2048
#define CNUM  128
#define MARGIN_F 0.3f
#define TOPK 12
#define MAXM 256
#define GBK 32          // K-tile (f16 elements), double-buffered
#define CAP 160         // topk candidate buffer per wave

// fallback-path tiling
#define BM 64
#define BN 64
#define BK 16
#define SLICES 8
#define COLS_PER_SLICE (NROWS / SLICES)

typedef _Float16 f16x8 __attribute__((ext_vector_type(8)));
typedef float    f32x4 __attribute__((ext_vector_type(4)));

// async global->LDS, 16 B per lane; lds dest = wave-uniform base + lane*16
#define GLD_LDS16(g, l)                                                        \
    __builtin_amdgcn_global_load_lds(                                          \
        (const __attribute__((address_space(1))) uint32_t*)(g),                \
        (__attribute__((address_space(3))) uint32_t*)(l), 16, 0, 0)

__device__ __forceinline__ uint32_t rnd_u32(uint32_t row, uint32_t k) {
    uint64_t x = ((uint64_t)row << 32) ^ (0x9E3779B97F4A7C15ULL * (uint64_t)(k + 1u));
    x ^= x >> 33; x *= 0xff51afd7ed558ccdULL;
    x ^= x >> 33; x *= 0xc4ceb9fe1a85ec53ULL;
    x ^= x >> 33;
    return (uint32_t)x;
}

// ---------- fast path: FUSED setup — prep (convert+rowsq) / predcls / classlist ----
__global__ void setup_kernel(const float* __restrict__ X, _Float16* __restrict__ Xh,
                             float* __restrict__ sq,
                             const float* __restrict__ P, int* __restrict__ cls,
                             const int* __restrict__ tgt,
                             int* __restrict__ cnt, int* __restrict__ members) {
    int b = blockIdx.x, tid = threadIdx.x;
    int wave = tid >> 6, lane = tid & 63;

    if (b < NROWS) {
        __shared__ float ws[4];
        int row = b;
        const float4* xp = (const float4*)(X + (size_t)row * DIM);
        float4 a = xp[tid * 2], v2 = xp[tid * 2 + 1];
        float s = a.x * a.x + a.y * a.y + a.z * a.z + a.w * a.w
                + v2.x * v2.x + v2.y * v2.y + v2.z * v2.z + v2.w * v2.w;
        _Float16 h[8] = { (_Float16)a.x, (_Float16)a.y, (_Float16)a.z, (_Float16)a.w,
                          (_Float16)v2.x, (_Float16)v2.y, (_Float16)v2.z, (_Float16)v2.w };
        ((uint4*)(Xh + (size_t)row * DIM))[tid] = *(uint4*)h;
        for (int off = 32; off; off >>= 1) s += __shfl_xor(s, off, 64);
        if (lane == 0) ws[wave] = s;
        __syncthreads();
        if (tid == 0) sq[row] = ws[0] + ws[1] + ws[2] + ws[3];
    } else if (b < NROWS + NROWS / 4) {
        int row = (b - NROWS) * 4 + wave;
        const float* p = P + (size_t)row * CNUM;
        float v0 = p[lane]; int i0 = lane;
        float v1 = p[lane + 64];
        if (v1 > v0) { v0 = v1; i0 = lane + 64; }
        for (int off = 1; off < 64; off <<= 1) {
            float ov = __shfl_xor(v0, off, 64);
            int   oi = __shfl_xor(i0, off, 64);
            if (ov > v0 || (ov == v0 && oi < i0)) { v0 = ov; i0 = oi; }
        }
        if (lane == 0) cls[row] = i0;
    } else {
        int c = (b - NROWS - NROWS / 4) * 4 + wave;
        if (c >= CNUM) return;
        int k = 0;
        for (int base = 0; base < NROWS; base += 64) {
            int i = base + lane;
            bool m = (tgt[i] == c);
            unsigned long long mask = __ballot(m);
            if (m) {
                int pos = k + __popcll(mask & ((1ull << lane) - 1ull));
                if (pos < MAXM) members[c * MAXM + pos] = i;
            }
            k += __popcll(mask);
        }
        if (lane == 0) cnt[c] = (k < MAXM) ? k : MAXM;
    }
}

// ---------- fallback: row sum of squares ----------
__global__ void rowsq_kernel(const float* __restrict__ X, float* __restrict__ sq) {
    int wave = (blockIdx.x * blockDim.x + threadIdx.x) >> 6;
    int lane = threadIdx.x & 63;
    if (wave >= NROWS) return;
    const float4* xp = (const float4*)(X + (size_t)wave * DIM);
    float s = 0.f;
    for (int k = lane; k < DIM / 4; k += 64) {
        float4 v = xp[k];
        s += v.x * v.x + v.y * v.y + v.z * v.z + v.w * v.w;
    }
    for (int off = 32; off; off >>= 1) s += __shfl_xor(s, off, 64);
    if (lane == 0) sq[wave] = s;
}

// ---------- fallback: predcls ----------
__global__ void predcls_kernel(const float* __restrict__ P, int* __restrict__ cls) {
    int row = (blockIdx.x * blockDim.x + threadIdx.x) >> 6;
    int lane = threadIdx.x & 63;
    if (row >= NROWS) return;
    const float* p = P + (size_t)row * CNUM;
    float v0 = p[lane]; int i0 = lane;
    float v1 = p[lane + 64];
    if (v1 > v0) { v0 = v1; i0 = lane + 64; }
    for (int off = 1; off < 64; off <<= 1) {
        float ov = __shfl_xor(v0, off, 64);
        int   oi = __shfl_xor(i0, off, 64);
        if (ov > v0 || (ov == v0 && oi < i0)) { v0 = ov; i0 = oi; }
    }
    if (lane == 0) cls[row] = i0;
}

// ---------- fallback: classlist ----------
__global__ void classlist_kernel(const int* __restrict__ tgt,
                                 int* __restrict__ cnt, int* __restrict__ members) {
    int c = (blockIdx.x * blockDim.x + threadIdx.x) >> 6;
    int lane = threadIdx.x & 63;
    if (c >= CNUM) return;
    int k = 0;
    for (int base = 0; base < NROWS; base += 64) {
        int i = base + lane;
        bool m = (tgt[i] == c);
        unsigned long long mask = __ballot(m);
        if (m) {
            int pos = k + __popcll(mask & ((1ull << lane) - 1ull));
            if (pos < MAXM) members[c * MAXM + pos] = i;
        }
        k += __popcll(mask);
    }
    if (lane == 0) cnt[c] = (k < MAXM) ? k : MAXM;
}

// ---------- fast path: f16 MFMA Gram, BK=32 double-buffered (R11 exact, 78 us) ----
// Measured invariant (R5/R7/R8/R11/R12): dur ~= hbm_bytes / 1.85 TB/s regardless
// of occupancy/tile/buffering. 128-tile minimizes traffic (146 MB) -> keep.
__launch_bounds__(256, 4)
__global__ void mfma_dist_kernel(const _Float16* __restrict__ Xh,
                                 const float* __restrict__ sq, const int* __restrict__ tgt,
                                 float* __restrict__ dist) {
    __shared__ _Float16 Ah[2][128 * GBK];   // 2 x 8 KB
    __shared__ _Float16 Bh[2][128 * GBK];   // 2 x 8 KB
    __shared__ float    trb[4][16 * 17];
    __shared__ float    sqA[128], sqB[128];
    __shared__ int      tgA[128], tgB[128];

    int b = blockIdx.x;
    int br = 0, S = 0;
    while (b >= S + (32 - br)) { S += 32 - br; br++; }
    int bc = br + (b - S);

    int r0 = br * 128, c0 = bc * 128;
    int tid = threadIdx.x;
    int wave = tid >> 6, lane = tid & 63;
    int wr = wave >> 1, wc = wave & 1;

    if (tid < 128) { sqA[tid] = sq[r0 + tid]; tgA[tid] = tgt[r0 + tid]; }
    else { int t = tid - 128; sqB[t] = sq[c0 + t]; tgB[t] = tgt[c0 + t]; }

    f32x4 acc[4][4];
#pragma unroll
    for (int i = 0; i < 4; i++)
#pragma unroll
        for (int j = 0; j < 4; j++) acc[i][j] = (f32x4)0.f;

    const _Float16* gA[2]; const _Float16* gB[2];
    int ldsOff[2];
#pragma unroll
    for (int q = 0; q < 2; q++) {
        int rl = wave * 32 + q * 16 + (lane >> 2);        // local row 0..127
        int slot = lane & 3;                              // dest 16B slot in row
        int c = (slot - ((rl >> 1) & 3)) & 3;             // swizzled source chunk
        gA[q] = Xh + (size_t)(r0 + rl) * DIM + c * 8;
        gB[q] = Xh + (size_t)(c0 + rl) * DIM + c * 8;
        ldsOff[q] = (wave * 32 + q * 16) * GBK;           // wave-uniform base
    }

    auto stage = [&](int buf, int kOff) {
#pragma unroll
        for (int q = 0; q < 2; q++) {
            GLD_LDS16(gA[q] + kOff, &Ah[buf][ldsOff[q]]);
            GLD_LDS16(gB[q] + kOff, &Bh[buf][ldsOff[q]]);
        }
    };

    stage(0, 0);
    int fr = lane & 15, fq = lane >> 4;

    for (int it = 0; it < DIM / GBK; it++) {              // 64 iterations
        int cur = it & 1;
        __syncthreads();                                  // prefetch drained; buffer safe
        if (it + 1 < DIM / GBK) stage(cur ^ 1, (it + 1) * GBK);
        f16x8 af[4], bf[4];
#pragma unroll
        for (int i = 0; i < 4; i++) {
            int row = wr * 64 + i * 16 + fr;
            int slot = (fq + ((row >> 1) & 3)) & 3;
            af[i] = *(const f16x8*)&Ah[cur][row * GBK + slot * 8];
        }
#pragma unroll
        for (int j = 0; j < 4; j++) {
            int col = wc * 64 + j * 16 + fr;
            int slot = (fq + ((col >> 1) & 3)) & 3;
            bf[j] = *(const f16x8*)&Bh[cur][col * GBK + slot * 8];
        }
#pragma unroll
        for (int i = 0; i < 4; i++)
#pragma unroll
            for (int j = 0; j < 4; j++)
                acc[i][j] = __builtin_amdgcn_mfma_f32_16x16x32_f16(af[i], bf[j], acc[i][j], 0, 0, 0);
    }

    // epilogue: d2 = sqA+sqB-2*dot, mask positives; NT direct + NT transposed mirror
    float* tb = trb[wave];
#pragma unroll
    for (int i = 0; i < 4; i++) {
#pragma unroll
        for (int j = 0; j < 4; j++) {
            int lcol = wc * 64 + j * 16 + fr;
            float d[4];
#pragma unroll
            for (int r = 0; r < 4; r++) {
                int lrow = wr * 64 + i * 16 + fq * 4 + r;
                float v = sqA[lrow] + sqB[lcol] - 2.f * acc[i][j][r];
                if (tgA[lrow] == tgB[lcol]) v = INFINITY;
                d[r] = v;
                __builtin_nontemporal_store(v, &dist[(size_t)(r0 + lrow) * NROWS + (c0 + lcol)]);
            }
            if (br != bc) {
#pragma unroll
                for (int r = 0; r < 4; r++) tb[fr * 17 + fq * 4 + r] = d[r];
#pragma unroll
                for (int r = 0; r < 4; r++) {
                    float v = tb[(fq * 4 + r) * 17 + fr];
                    int grow = c0 + wc * 64 + j * 16 + fq * 4 + r;
                    int gcol = r0 + wr * 64 + i * 16 + fr;
                    __builtin_nontemporal_store(v, &dist[(size_t)grow * NROWS + gcol]);
                }
            }
        }
    }
}

// ---------- fast path: FUSED per-row top-12 + triplet logic (one wave per row) ----
// Phase 1 = R8 pivot-filter topk, but the sorted 12-list lands in wave-private
// LDS (no global round trip). Phase 2 = R11 rowlogic inline in the same wave.
__launch_bounds__(256)
__global__ void topk_logic_kernel(const float* __restrict__ dist,
                                  const _Float16* __restrict__ Xh, const float* __restrict__ sq,
                                  const float* __restrict__ prob, const float* __restrict__ thr_p,
                                  const int* __restrict__ tgt, const int* __restrict__ pred_cls,
                                  const int* __restrict__ class_cnt, const int* __restrict__ class_mem,
                                  float* __restrict__ row_loss, int* __restrict__ row_corr) {
    __shared__ float cbv[4][CAP];
    __shared__ int   cbi[4][CAP];
    __shared__ float stv[4][TOPK];
    __shared__ int   sti[4][TOPK];
    int wave = threadIdx.x >> 6, lane = threadIdx.x & 63;
    int row = blockIdx.x * 4 + wave;
    const f32x4* d = (const f32x4*)(dist + (size_t)row * NROWS);

    // ---- phase 1: top-12 ----
    f32x4 v[16];
#pragma unroll
    for (int t = 0; t < 16; t++) v[t] = __builtin_nontemporal_load(&d[t * 64 + lane]);

    float lmin = INFINITY, lmax = -INFINITY, lsum = 0.f;
    int lcnt = 0;
#pragma unroll
    for (int t = 0; t < 16; t++) {
#pragma unroll
        for (int c = 0; c < 4; c++) {
            float x = v[t][c];
            bool fin = x < INFINITY;
            lmin = fminf(lmin, x);
            lmax = fmaxf(lmax, fin ? x : -INFINITY);
            lsum += fin ? x : 0.f;
            lcnt += fin ? 1 : 0;
        }
    }
    for (int off = 32; off; off >>= 1) {
        lmin = fminf(lmin, __shfl_xor(lmin, off, 64));
        lmax = fmaxf(lmax, __shfl_xor(lmax, off, 64));
        lsum += __shfl_xor(lsum, off, 64);
        lcnt += __shfl_xor(lcnt, off, 64);
    }
    float mu = lsum / (float)(lcnt > 0 ? lcnt : 1);

    float lo = lmin, hi = lmax + 1.0f;
    float tau = lmin + 0.3f * (mu - lmin);
    if (!(tau > lo && tau < hi)) tau = 0.5f * (lo + hi);
    for (int it = 0; it < 32; it++) {
        int lc = 0;
#pragma unroll
        for (int t = 0; t < 16; t++) {
            lc += (v[t][0] < tau) + (v[t][1] < tau) + (v[t][2] < tau) + (v[t][3] < tau);
        }
        for (int off = 32; off; off >>= 1) lc += __shfl_xor(lc, off, 64);
        if (lc >= TOPK && lc <= CAP) break;
        if (lc < TOPK) lo = tau; else hi = tau;
        tau = 0.5f * (lo + hi);
    }

    int cnt = 0;
#pragma unroll
    for (int t = 0; t < 16; t++) {
#pragma unroll
        for (int c = 0; c < 4; c++) {
            float x = v[t][c];
            bool p = x < tau;
            unsigned long long mk = __ballot(p);
            if (p) {
                int pos = cnt + __popcll(mk & ((1ull << lane) - 1ull));
                if (pos < CAP) {
                    cbv[wave][pos] = x;
                    cbi[wave][pos] = (t * 64 + lane) * 4 + c;
                }
            }
            cnt += __popcll(mk);
        }
    }
    if (cnt > CAP) cnt = CAP;

    float mv[3]; int mi[3];
#pragma unroll
    for (int r = 0; r < 3; r++) {
        int p = r * 64 + lane;
        bool ok = p < cnt;
        mv[r] = ok ? cbv[wave][p] : INFINITY;
        mi[r] = ok ? cbi[wave][p] : 0x7FFFFFFF;
    }

    for (int t = 0; t < TOPK; t++) {
        float bv = mv[0]; int bi = mi[0];
        if (mv[1] < bv || (mv[1] == bv && mi[1] < bi)) { bv = mv[1]; bi = mi[1]; }
        if (mv[2] < bv || (mv[2] == bv && mi[2] < bi)) { bv = mv[2]; bi = mi[2]; }
        for (int off = 32; off; off >>= 1) {
            float ov = __shfl_xor(bv, off, 64);
            int   oi = __shfl_xor(bi, off, 64);
            if (ov < bv || (ov == bv && oi < bi)) { bv = ov; bi = oi; }
        }
        if (lane == 0) {
            stv[wave][t] = bv;
            sti[wave][t] = (bi >= 0 && bi < NROWS) ? bi : 0;
        }
#pragma unroll
        for (int r = 0; r < 3; r++)
            if (mi[r] == bi) { mv[r] = INFINITY; mi[r] = 0x7FFFFFFF; }
    }
    // wave-private LDS: lane0's writes ordered before this wave's reads (R2-proven)

    // ---- phase 2: triplet logic for row `row` (wave-uniform) ----
    int i = row;
    float thr = *thr_p;
    int c = tgt[i];
    int cc = class_cnt[c];
    const int* mem = class_mem + c * MAXM;

    int pos_i = 0;
    for (int k = 0; k < cc; k++) { if (mem[k] == i) { pos_i = k; break; } }

    int rp = 0;
    if (cc > 1) {
        uint32_t r = rnd_u32((uint32_t)i, 0x9111u) % (uint32_t)(cc - 1);
        if ((int)r >= pos_i) r++;
        rp = mem[r];
    }

    int hn = sti[wave][0];
    float an0 = sqrtf(fmaxf(stv[wave][0], 1e-12f));
    bool p_neg = prob[hn] >= thr;
    bool is_FN = (pred_cls[hn] == c);

    int sel = 11;
    for (int k = 1; k <= 11; k++) {
        int cd = sti[wave][k];
        if (prob[cd] >= thr) { sel = k; break; }
    }
    float anB = sqrtf(fmaxf(stv[wave][sel], 1e-12f));

    int first_valid = -1, last_draw = 0;
    for (int k = 0; k < 6; k++) {
        uint32_t r = rnd_u32((uint32_t)i, 0xD000u + (uint32_t)k) % (uint32_t)(cc > 0 ? cc : 1);
        int dk = mem[r];
        last_draw = dk;
        if (first_valid < 0 && dk != i && prob[dk] >= thr) first_valid = dk;
    }
    int rp_new = (first_valid >= 0) ? first_valid : last_draw;
    bool p_pos = prob[rp] >= thr;

    const f16x8* xi = (const f16x8*)(Xh + (size_t)i * DIM);
    const f16x8* xr = (const f16x8*)(Xh + (size_t)rp * DIM);
    const f16x8* xn = (const f16x8*)(Xh + (size_t)rp_new * DIM);
    float s1 = 0.f, s2 = 0.f;
    for (int k = lane; k < DIM / 8; k += 64) {
        f16x8 a = xi[k], b2 = xr[k], d2 = xn[k];
#pragma unroll
        for (int e = 0; e < 8; e++) {
            float ax = (float)a[e];
            s1 += ax * (float)b2[e];
            s2 += ax * (float)d2[e];
        }
    }
    for (int off = 32; off; off >>= 1) {
        s1 += __shfl_xor(s1, off, 64);
        s2 += __shfl_xor(s2, off, 64);
    }
    if (lane == 0) {
        float ap0 = sqrtf(fmaxf(sq[i] + sq[rp]     - 2.f * s1, 1e-12f));
        float apC = sqrtf(fmaxf(sq[i] + sq[rp_new] - 2.f * s2, 1e-12f));
        float apB = (ap0 + an0) * 0.5f;
        float anC = (ap0 + an0) * 0.5f;
        bool useB = p_pos && !p_neg && is_FN;
        bool useC = (!p_pos && p_neg) || (!p_pos && !p_neg && !is_FN);
        bool inverse = !p_pos && !p_neg && is_FN;
        float ap = useB ? apB : (useC ? apC : ap0);
        float an = useB ? anB : (useC ? anC : an0);
        float pl = inverse ? fmaxf(an - ap + MARGIN_F, 0.f)
                           : fmaxf(ap - an + MARGIN_F, 0.f);
        bool conf = prob[i] >= thr;
        row_loss[i] = conf ? pl : 0.f;
        row_corr[i] = (conf && (an >= ap)) ? 1 : 0;
    }
}

// ---------- fallback path (proven R1): fused fp32 GEMM + per-row top-12 ----------
__launch_bounds__(256)
__global__ void dist_topk_kernel(const float* __restrict__ X, const float* __restrict__ sq,
                                 const int* __restrict__ tgt,
                                 float* __restrict__ part_v, int* __restrict__ part_i) {
    __shared__ float As[BK][BM];
    __shared__ float Bs[BK][BN];
    __shared__ float Cs[BM][BN + 1];
    __shared__ float sqA[BM], sqB[BN];
    __shared__ int   tgA[BM], tgB[BN];

    int rowBase = blockIdx.x * BM;
    int slice = blockIdx.y;
    int tid = threadIdx.x;
    int tx = tid & 15, ty = tid >> 4;

    if (tid < BM) { sqA[tid] = sq[rowBase + tid]; tgA[tid] = tgt[rowBase + tid]; }

    float lv[TOPK]; int li[TOPK];
#pragma unroll
    for (int k = 0; k < TOPK; k++) { lv[k] = INFINITY; li[k] = -1; }

    for (int jt = 0; jt < COLS_PER_SLICE / BN; jt++) {
        int colBase = slice * COLS_PER_SLICE + jt * BN;
        __syncthreads();
        if (tid < BN) { sqB[tid] = sq[colBase + tid]; tgB[tid] = tgt[colBase + tid]; }

        float acc[4][4] = {};
        for (int kb = 0; kb < DIM; kb += BK) {
            int r  = tid >> 2;
            int kk = (tid & 3) * 4;
            float4 va = *(const float4*)(X + (size_t)(rowBase + r) * DIM + kb + kk);
            As[kk + 0][r] = va.x; As[kk + 1][r] = va.y; As[kk + 2][r] = va.z; As[kk + 3][r] = va.w;
            float4 vb = *(const float4*)(X + (size_t)(colBase + r) * DIM + kb + kk);
            Bs[kk + 0][r] = vb.x; Bs[kk + 1][r] = vb.y; Bs[kk + 2][r] = vb.z; Bs[kk + 3][r] = vb.w;
            __syncthreads();
#pragma unroll
            for (int k = 0; k < BK; k++) {
                float a[4], b2[4];
                *(float4*)a = *(const float4*)&As[k][ty * 4];
                *(float4*)b2 = *(const float4*)&Bs[k][tx * 4];
#pragma unroll
                for (int i2 = 0; i2 < 4; i2++)
#pragma unroll
                    for (int j2 = 0; j2 < 4; j2++)
                        acc[i2][j2] += a[i2] * b2[j2];
            }
            __syncthreads();
        }
#pragma unroll
        for (int i2 = 0; i2 < 4; i2++) {
            int r = ty * 4 + i2;
#pragma unroll
            for (int j2 = 0; j2 < 4; j2++) {
                int c = tx * 4 + j2;
                float d2 = sqA[r] + sqB[c] - 2.f * acc[i2][j2];
                if (tgA[r] == tgB[c]) d2 = INFINITY;
                Cs[r][c] = d2;
            }
        }
        __syncthreads();
        if (tid < BM) {
            int r = tid;
            for (int c = 0; c < BN; c++) {
                float v = Cs[r][c];
                if (v < lv[TOPK - 1]) {
                    float nv = v; int ni = colBase + c;
#pragma unroll
                    for (int p = 0; p < TOPK; p++) {
                        if (nv < lv[p]) {
                            float tv = lv[p]; int ti = li[p];
                            lv[p] = nv; li[p] = ni;
                            nv = tv; ni = ti;
                        }
                    }
                }
            }
        }
    }
    if (tid < BM) {
        int r = tid;
#pragma unroll
        for (int k = 0; k < TOPK; k++) {
            size_t o = ((size_t)(rowBase + r) * SLICES + slice) * TOPK + k;
            part_v[o] = lv[k];
            part_i[o] = li[k];
        }
    }
}

__global__ void topk_merge_kernel(const float* __restrict__ part_v, const int* __restrict__ part_i,
                                  float* __restrict__ top_v, int* __restrict__ top_i) {
    int row = blockIdx.x * blockDim.x + threadIdx.x;
    if (row >= NROWS) return;
    float lv[TOPK]; int li[TOPK];
#pragma unroll
    for (int k = 0; k < TOPK; k++) { lv[k] = INFINITY; li[k] = -1; }
    for (int s = 0; s < SLICES; s++) {
        for (int k = 0; k < TOPK; k++) {
            size_t o = ((size_t)row * SLICES + s) * TOPK + k;
            float v = part_v[o];
            if (!(v < lv[TOPK - 1])) break;
            int idx = part_i[o];
            float nv = v; int ni = idx;
#pragma unroll
            for (int p = 0; p < TOPK; p++) {
                if (nv < lv[p]) {
                    float tv = lv[p]; int ti = li[p];
                    lv[p] = nv; li[p] = ni;
                    nv = tv; ni = ti;
                }
            }
        }
    }
#pragma unroll
    for (int k = 0; k < TOPK; k++) {
        top_v[(size_t)row * TOPK + k] = lv[k];
        top_i[(size_t)row * TOPK + k] = li[k];
    }
}

// fallback rowlogic on fp32 X
__global__ void rowlogic_f32_kernel(const float* __restrict__ X, const float* __restrict__ sq,
                                    const float* __restrict__ prob, const float* __restrict__ thr_p,
                                    const int* __restrict__ tgt, const int* __restrict__ pred_cls,
                                    const int* __restrict__ class_cnt, const int* __restrict__ class_mem,
                                    const float* __restrict__ top_v, const int* __restrict__ top_i,
                                    float* __restrict__ row_loss, int* __restrict__ row_corr) {
    int i = (blockIdx.x * blockDim.x + threadIdx.x) >> 6;
    int lane = threadIdx.x & 63;
    if (i >= NROWS) return;
    float thr = *thr_p;

    int c = tgt[i];
    int cc = class_cnt[c];
    const int* mem = class_mem + c * MAXM;

    int pos_i = 0;
    for (int k = 0; k < cc; k++) { if (mem[k] == i) { pos_i = k; break; } }

    int rp = 0;
    if (cc > 1) {
        uint32_t r = rnd_u32((uint32_t)i, 0x9111u) % (uint32_t)(cc - 1);
        if ((int)r >= pos_i) r++;
        rp = mem[r];
    }

    int hn = top_i[(size_t)i * TOPK + 0];
    float an0 = sqrtf(fmaxf(top_v[(size_t)i * TOPK + 0], 1e-12f));
    bool p_neg = prob[hn] >= thr;
    bool is_FN = (pred_cls[hn] == c);

    int sel = 11;
    for (int k = 1; k <= 11; k++) {
        int cd = top_i[(size_t)i * TOPK + k];
        if (prob[cd] >= thr) { sel = k; break; }
    }
    float anB = sqrtf(fmaxf(top_v[(size_t)i * TOPK + sel], 1e-12f));

    int first_valid = -1, last_draw = 0;
    for (int k = 0; k < 6; k++) {
        uint32_t r = rnd_u32((uint32_t)i, 0xD000u + (uint32_t)k) % (uint32_t)(cc > 0 ? cc : 1);
        int dk = mem[r];
        last_draw = dk;
        if (first_valid < 0 && dk != i && prob[dk] >= thr) first_valid = dk;
    }
    int rp_new = (first_valid >= 0) ? first_valid : last_draw;
    bool p_pos = prob[rp] >= thr;

    const float4* xi = (const float4*)(X + (size_t)i * DIM);
    const float4* xr = (const float4*)(X + (size_t)rp * DIM);
    const float4* xn = (const float4*)(X + (size_t)rp_new * DIM);
    float s1 = 0.f, s2 = 0.f;
    for (int k = lane; k < DIM / 4; k += 64) {
        float4 a = xi[k], b = xr[k], d = xn[k];
        s1 += a.x * b.x + a.y * b.y + a.z * b.z + a.w * b.w;
        s2 += a.x * d.x + a.y * d.y + a.z * d.z + a.w * d.w;
    }
    for (int off = 32; off; off >>= 1) {
        s1 += __shfl_xor(s1, off, 64);
        s2 += __shfl_xor(s2, off, 64);
    }
    if (lane == 0) {
        float ap0 = sqrtf(fmaxf(sq[i] + sq[rp]     - 2.f * s1, 1e-12f));
        float apC = sqrtf(fmaxf(sq[i] + sq[rp_new] - 2.f * s2, 1e-12f));
        float apB = (ap0 + an0) * 0.5f;
        float anC = (ap0 + an0) * 0.5f;
        bool useB = p_pos && !p_neg && is_FN;
        bool useC = (!p_pos && p_neg) || (!p_pos && !p_neg && !is_FN);
        bool inverse = !p_pos && !p_neg && is_FN;
        float ap = useB ? apB : (useC ? apC : ap0);
        float an = useB ? anB : (useC ? anC : an0);
        float pl = inverse ? fmaxf(an - ap + MARGIN_F, 0.f)
                           : fmaxf(ap - an + MARGIN_F, 0.f);
        bool conf = prob[i] >= thr;
        row_loss[i] = conf ? pl : 0.f;
        row_corr[i] = (conf && (an >= ap)) ? 1 : 0;
    }
}

// ---------- final reduction ----------
__global__ void reduce_kernel(const float* __restrict__ row_loss, const int* __restrict__ row_corr,
                              const float* __restrict__ prob, const float* __restrict__ thr_p,
                              float* __restrict__ out) {
    __shared__ float sl[256];
    __shared__ int   sc[256];
    __shared__ int   sn[256];
    float thr = *thr_p;
    int tid = threadIdx.x;
    float l = 0.f; int corr = 0, cnt = 0;
    for (int i = tid; i < NROWS; i += 256) {
        l += row_loss[i];
        corr += row_corr[i];
        cnt += (prob[i] >= thr) ? 1 : 0;
    }
    sl[tid] = l; sc[tid] = corr; sn[tid] = cnt;
    __syncthreads();
    for (int off = 128; off; off >>= 1) {
        if (tid < off) {
            sl[tid] += sl[tid + off];
            sc[tid] += sc[tid + off];
            sn[tid] += sn[tid + off];
        }
        __syncthreads();
    }
    if (tid == 0) {
        int cn = sn[0];
        float loss = (cn > 0) ? (sl[0] / (float)(cn > 1 ? cn : 1)) : 0.f;
        out[0] = loss;
        out[1] = (float)sc[0];
        out[2] = (float)cn;
    }
}

extern "C" void kernel_launch(void* const* d_in, const int* in_sizes, int n_in,
                              void* d_out, int out_size, void* d_ws, size_t ws_size,
                              hipStream_t stream) {
    const float* X    = (const float*)d_in[0];
    const float* P    = (const float*)d_in[1];
    const int*   tgt  = (const int*)d_in[2];
    const float* prob = (const float*)d_in[4];
    const float* thr  = (const float*)d_in[5];
    float* out = (float*)d_out;

    char* w = (char*)d_ws;
    auto alloc = [&](size_t bytes) {
        char* p = w;
        w += (bytes + 255) & ~(size_t)255;
        return p;
    };
    float* sq        = (float*)alloc(NROWS * sizeof(float));
    int*   pred_cls  = (int*)  alloc(NROWS * sizeof(int));
    int*   class_cnt = (int*)  alloc(CNUM * sizeof(int));
    int*   class_mem = (int*)  alloc((size_t)CNUM * MAXM * sizeof(int));
    float* top_v     = (float*)alloc((size_t)NROWS * TOPK * sizeof(float));
    int*   top_i     = (int*)  alloc((size_t)NROWS * TOPK * sizeof(int));
    float* row_loss  = (float*)alloc(NROWS * sizeof(float));
    int*   row_corr  = (int*)  alloc(NROWS * sizeof(int));
    char*  var_base  = w;

    // fast path: Xh (16.8 MB) + fp32 dist (64 MB)
    size_t fast_need = (size_t)NROWS * DIM * 2 + (size_t)NROWS * NROWS * 4 + (1 << 20);
    bool fast = ((size_t)(var_base - (char*)d_ws) + fast_need) <= ws_size;

    if (fast) {
        _Float16* Xh   = (_Float16*)alloc((size_t)NROWS * DIM * 2);
        float*    dist = (float*)alloc((size_t)NROWS * NROWS * 4);
        setup_kernel<<<NROWS + NROWS / 4 + CNUM / 4, 256, 0, stream>>>(
            X, Xh, sq, P, pred_cls, tgt, class_cnt, class_mem);
        mfma_dist_kernel<<<528, 256, 0, stream>>>(Xh, sq, tgt, dist);
        topk_logic_kernel<<<NROWS / 4, 256, 0, stream>>>(dist, Xh, sq, prob, thr, tgt, pred_cls,
                                                         class_cnt, class_mem,
                                                         row_loss, row_corr);
    } else {
        rowsq_kernel<<<NROWS / 4, 256, 0, stream>>>(X, sq);
        predcls_kernel<<<NROWS / 4, 256, 0, stream>>>(P, pred_cls);
        classlist_kernel<<<CNUM / 4, 256, 0, stream>>>(tgt, class_cnt, class_mem);
        float* part_v = (float*)alloc((size_t)NROWS * SLICES * TOPK * sizeof(float));
        int*   part_i = (int*)  alloc((size_t)NROWS * SLICES * TOPK * sizeof(int));
        dist_topk_kernel<<<dim3(NROWS / BM, SLICES), 256, 0, stream>>>(X, sq, tgt, part_v, part_i);
        topk_merge_kernel<<<NROWS / 256, 256, 0, stream>>>(part_v, part_i, top_v, top_i);
        rowlogic_f32_kernel<<<NROWS / 4, 256, 0, stream>>>(X, sq, prob, thr, tgt, pred_cls,
                                                           class_cnt, class_mem, top_v, top_i,
                                                           row_loss, row_corr);
    }

    reduce_kernel<<<1, 256, 0, stream>>>(row_loss, row_corr, prob, thr, out);
}

// Round 14
// 209.028 us; speedup vs baseline: 1.1621x; 1.0256x over previous
//
#include <hip/hip_runtime.h>
#include <hip/hip_bf16.h>
#include <cstdint>
#include <cmath>

#define NROWS 4096
#define DIM   2048
#define CNUM  128
#define MARGIN_F 0.3f
#define TOPK 12
#define MAXM 256
#define GBK 32          // K-tile (f16 elements), double-buffered
#define CAP 160         // topk candidate buffer per wave

// fallback-path tiling
#define BM 64
#define BN 64
#define BK 16
#define SLICES 8
#define COLS_PER_SLICE (NROWS / SLICES)

typedef _Float16 f16x8 __attribute__((ext_vector_type(8)));
typedef float    f32x4 __attribute__((ext_vector_type(4)));

// async global->LDS, 16 B per lane; lds dest = wave-uniform base + lane*16
#define GLD_LDS16(g, l)                                                        \
    __builtin_amdgcn_global_load_lds(                                          \
        (const __attribute__((address_space(1))) uint32_t*)(g),                \
        (__attribute__((address_space(3))) uint32_t*)(l), 16, 0, 0)

__device__ __forceinline__ uint32_t rnd_u32(uint32_t row, uint32_t k) {
    uint64_t x = ((uint64_t)row << 32) ^ (0x9E3779B97F4A7C15ULL * (uint64_t)(k + 1u));
    x ^= x >> 33; x *= 0xff51afd7ed558ccdULL;
    x ^= x >> 33; x *= 0xc4ceb9fe1a85ec53ULL;
    x ^= x >> 33;
    return (uint32_t)x;
}

// ---------- fast path: FUSED setup — prep (convert+rowsq) / predcls / classlist ----
__global__ void setup_kernel(const float* __restrict__ X, _Float16* __restrict__ Xh,
                             float* __restrict__ sq,
                             const float* __restrict__ P, int* __restrict__ cls,
                             const int* __restrict__ tgt,
                             int* __restrict__ cnt, int* __restrict__ members) {
    int b = blockIdx.x, tid = threadIdx.x;
    int wave = tid >> 6, lane = tid & 63;

    if (b < NROWS) {
        __shared__ float ws[4];
        int row = b;
        const float4* xp = (const float4*)(X + (size_t)row * DIM);
        float4 a = xp[tid * 2], v2 = xp[tid * 2 + 1];
        float s = a.x * a.x + a.y * a.y + a.z * a.z + a.w * a.w
                + v2.x * v2.x + v2.y * v2.y + v2.z * v2.z + v2.w * v2.w;
        _Float16 h[8] = { (_Float16)a.x, (_Float16)a.y, (_Float16)a.z, (_Float16)a.w,
                          (_Float16)v2.x, (_Float16)v2.y, (_Float16)v2.z, (_Float16)v2.w };
        ((uint4*)(Xh + (size_t)row * DIM))[tid] = *(uint4*)h;
        for (int off = 32; off; off >>= 1) s += __shfl_xor(s, off, 64);
        if (lane == 0) ws[wave] = s;
        __syncthreads();
        if (tid == 0) sq[row] = ws[0] + ws[1] + ws[2] + ws[3];
    } else if (b < NROWS + NROWS / 4) {
        int row = (b - NROWS) * 4 + wave;
        const float* p = P + (size_t)row * CNUM;
        float v0 = p[lane]; int i0 = lane;
        float v1 = p[lane + 64];
        if (v1 > v0) { v0 = v1; i0 = lane + 64; }
        for (int off = 1; off < 64; off <<= 1) {
            float ov = __shfl_xor(v0, off, 64);
            int   oi = __shfl_xor(i0, off, 64);
            if (ov > v0 || (ov == v0 && oi < i0)) { v0 = ov; i0 = oi; }
        }
        if (lane == 0) cls[row] = i0;
    } else {
        int c = (b - NROWS - NROWS / 4) * 4 + wave;
        if (c >= CNUM) return;
        int k = 0;
        for (int base = 0; base < NROWS; base += 64) {
            int i = base + lane;
            bool m = (tgt[i] == c);
            unsigned long long mask = __ballot(m);
            if (m) {
                int pos = k + __popcll(mask & ((1ull << lane) - 1ull));
                if (pos < MAXM) members[c * MAXM + pos] = i;
            }
            k += __popcll(mask);
        }
        if (lane == 0) cnt[c] = (k < MAXM) ? k : MAXM;
    }
}

// ---------- fallback: row sum of squares ----------
__global__ void rowsq_kernel(const float* __restrict__ X, float* __restrict__ sq) {
    int wave = (blockIdx.x * blockDim.x + threadIdx.x) >> 6;
    int lane = threadIdx.x & 63;
    if (wave >= NROWS) return;
    const float4* xp = (const float4*)(X + (size_t)wave * DIM);
    float s = 0.f;
    for (int k = lane; k < DIM / 4; k += 64) {
        float4 v = xp[k];
        s += v.x * v.x + v.y * v.y + v.z * v.z + v.w * v.w;
    }
    for (int off = 32; off; off >>= 1) s += __shfl_xor(s, off, 64);
    if (lane == 0) sq[wave] = s;
}

// ---------- fallback: predcls ----------
__global__ void predcls_kernel(const float* __restrict__ P, int* __restrict__ cls) {
    int row = (blockIdx.x * blockDim.x + threadIdx.x) >> 6;
    int lane = threadIdx.x & 63;
    if (row >= NROWS) return;
    const float* p = P + (size_t)row * CNUM;
    float v0 = p[lane]; int i0 = lane;
    float v1 = p[lane + 64];
    if (v1 > v0) { v0 = v1; i0 = lane + 64; }
    for (int off = 1; off < 64; off <<= 1) {
        float ov = __shfl_xor(v0, off, 64);
        int   oi = __shfl_xor(i0, off, 64);
        if (ov > v0 || (ov == v0 && oi < i0)) { v0 = ov; i0 = oi; }
    }
    if (lane == 0) cls[row] = i0;
}

// ---------- fallback: classlist ----------
__global__ void classlist_kernel(const int* __restrict__ tgt,
                                 int* __restrict__ cnt, int* __restrict__ members) {
    int c = (blockIdx.x * blockDim.x + threadIdx.x) >> 6;
    int lane = threadIdx.x & 63;
    if (c >= CNUM) return;
    int k = 0;
    for (int base = 0; base < NROWS; base += 64) {
        int i = base + lane;
        bool m = (tgt[i] == c);
        unsigned long long mask = __ballot(m);
        if (m) {
            int pos = k + __popcll(mask & ((1ull << lane) - 1ull));
            if (pos < MAXM) members[c * MAXM + pos] = i;
        }
        k += __popcll(mask);
    }
    if (lane == 0) cnt[c] = (k < MAXM) ? k : MAXM;
}

// ---------- fast path: f16 MFMA Gram (R13 structure) + XCD swizzle, plain stores ---
// Changes vs R13: (1) XCD-aware tile swizzle b' = (b&7)*66 + (b>>3) — each XCD
// gets 66 consecutive triangle tiles for L2 row-panel reuse; (2) PLAIN stores so
// dist allocates in L3 and the immediately-following topk reads it at L3 BW.
__launch_bounds__(256, 4)
__global__ void mfma_dist_kernel(const _Float16* __restrict__ Xh,
                                 const float* __restrict__ sq, const int* __restrict__ tgt,
                                 float* __restrict__ dist) {
    __shared__ _Float16 Ah[2][128 * GBK];   // 2 x 8 KB
    __shared__ _Float16 Bh[2][128 * GBK];   // 2 x 8 KB
    __shared__ float    trb[4][16 * 17];
    __shared__ float    sqA[128], sqB[128];
    __shared__ int      tgA[128], tgB[128];

    int b = blockIdx.x;
    b = (b & 7) * 66 + (b >> 3);            // XCD-aware: 528 = 8 x 66
    int br = 0, S = 0;
    while (b >= S + (32 - br)) { S += 32 - br; br++; }
    int bc = br + (b - S);

    int r0 = br * 128, c0 = bc * 128;
    int tid = threadIdx.x;
    int wave = tid >> 6, lane = tid & 63;
    int wr = wave >> 1, wc = wave & 1;

    if (tid < 128) { sqA[tid] = sq[r0 + tid]; tgA[tid] = tgt[r0 + tid]; }
    else { int t = tid - 128; sqB[t] = sq[c0 + t]; tgB[t] = tgt[c0 + t]; }

    f32x4 acc[4][4];
#pragma unroll
    for (int i = 0; i < 4; i++)
#pragma unroll
        for (int j = 0; j < 4; j++) acc[i][j] = (f32x4)0.f;

    const _Float16* gA[2]; const _Float16* gB[2];
    int ldsOff[2];
#pragma unroll
    for (int q = 0; q < 2; q++) {
        int rl = wave * 32 + q * 16 + (lane >> 2);        // local row 0..127
        int slot = lane & 3;                              // dest 16B slot in row
        int c = (slot - ((rl >> 1) & 3)) & 3;             // swizzled source chunk
        gA[q] = Xh + (size_t)(r0 + rl) * DIM + c * 8;
        gB[q] = Xh + (size_t)(c0 + rl) * DIM + c * 8;
        ldsOff[q] = (wave * 32 + q * 16) * GBK;           // wave-uniform base
    }

    auto stage = [&](int buf, int kOff) {
#pragma unroll
        for (int q = 0; q < 2; q++) {
            GLD_LDS16(gA[q] + kOff, &Ah[buf][ldsOff[q]]);
            GLD_LDS16(gB[q] + kOff, &Bh[buf][ldsOff[q]]);
        }
    };

    stage(0, 0);
    int fr = lane & 15, fq = lane >> 4;

    for (int it = 0; it < DIM / GBK; it++) {              // 64 iterations
        int cur = it & 1;
        __syncthreads();                                  // prefetch drained; buffer safe
        if (it + 1 < DIM / GBK) stage(cur ^ 1, (it + 1) * GBK);
        f16x8 af[4], bf[4];
#pragma unroll
        for (int i = 0; i < 4; i++) {
            int row = wr * 64 + i * 16 + fr;
            int slot = (fq + ((row >> 1) & 3)) & 3;
            af[i] = *(const f16x8*)&Ah[cur][row * GBK + slot * 8];
        }
#pragma unroll
        for (int j = 0; j < 4; j++) {
            int col = wc * 64 + j * 16 + fr;
            int slot = (fq + ((col >> 1) & 3)) & 3;
            bf[j] = *(const f16x8*)&Bh[cur][col * GBK + slot * 8];
        }
#pragma unroll
        for (int i = 0; i < 4; i++)
#pragma unroll
            for (int j = 0; j < 4; j++)
                acc[i][j] = __builtin_amdgcn_mfma_f32_16x16x32_f16(af[i], bf[j], acc[i][j], 0, 0, 0);
    }

    // epilogue: d2 = sqA+sqB-2*dot, mask positives; plain direct + transposed mirror
    float* tb = trb[wave];
#pragma unroll
    for (int i = 0; i < 4; i++) {
#pragma unroll
        for (int j = 0; j < 4; j++) {
            int lcol = wc * 64 + j * 16 + fr;
            float d[4];
#pragma unroll
            for (int r = 0; r < 4; r++) {
                int lrow = wr * 64 + i * 16 + fq * 4 + r;
                float v = sqA[lrow] + sqB[lcol] - 2.f * acc[i][j][r];
                if (tgA[lrow] == tgB[lcol]) v = INFINITY;
                d[r] = v;
                dist[(size_t)(r0 + lrow) * NROWS + (c0 + lcol)] = v;
            }
            if (br != bc) {
#pragma unroll
                for (int r = 0; r < 4; r++) tb[fr * 17 + fq * 4 + r] = d[r];
#pragma unroll
                for (int r = 0; r < 4; r++) {
                    float v = tb[(fq * 4 + r) * 17 + fr];
                    int grow = c0 + wc * 64 + j * 16 + fq * 4 + r;
                    int gcol = r0 + wr * 64 + i * 16 + fr;
                    dist[(size_t)grow * NROWS + gcol] = v;
                }
            }
        }
    }
}

// ---------- fast path: FUSED per-row top-12 + triplet logic (one wave per row) ----
// Plain dist loads: dist was just written with L3 allocation -> L3-resident read.
__launch_bounds__(256)
__global__ void topk_logic_kernel(const float* __restrict__ dist,
                                  const _Float16* __restrict__ Xh, const float* __restrict__ sq,
                                  const float* __restrict__ prob, const float* __restrict__ thr_p,
                                  const int* __restrict__ tgt, const int* __restrict__ pred_cls,
                                  const int* __restrict__ class_cnt, const int* __restrict__ class_mem,
                                  float* __restrict__ row_loss, int* __restrict__ row_corr) {
    __shared__ float cbv[4][CAP];
    __shared__ int   cbi[4][CAP];
    __shared__ float stv[4][TOPK];
    __shared__ int   sti[4][TOPK];
    int wave = threadIdx.x >> 6, lane = threadIdx.x & 63;
    int row = blockIdx.x * 4 + wave;
    const f32x4* d = (const f32x4*)(dist + (size_t)row * NROWS);

    // ---- phase 1: top-12 ----
    f32x4 v[16];
#pragma unroll
    for (int t = 0; t < 16; t++) v[t] = d[t * 64 + lane];

    float lmin = INFINITY, lmax = -INFINITY, lsum = 0.f;
    int lcnt = 0;
#pragma unroll
    for (int t = 0; t < 16; t++) {
#pragma unroll
        for (int c = 0; c < 4; c++) {
            float x = v[t][c];
            bool fin = x < INFINITY;
            lmin = fminf(lmin, x);
            lmax = fmaxf(lmax, fin ? x : -INFINITY);
            lsum += fin ? x : 0.f;
            lcnt += fin ? 1 : 0;
        }
    }
    for (int off = 32; off; off >>= 1) {
        lmin = fminf(lmin, __shfl_xor(lmin, off, 64));
        lmax = fmaxf(lmax, __shfl_xor(lmax, off, 64));
        lsum += __shfl_xor(lsum, off, 64);
        lcnt += __shfl_xor(lcnt, off, 64);
    }
    float mu = lsum / (float)(lcnt > 0 ? lcnt : 1);

    float lo = lmin, hi = lmax + 1.0f;
    float tau = lmin + 0.3f * (mu - lmin);
    if (!(tau > lo && tau < hi)) tau = 0.5f * (lo + hi);
    for (int it = 0; it < 32; it++) {
        int lc = 0;
#pragma unroll
        for (int t = 0; t < 16; t++) {
            lc += (v[t][0] < tau) + (v[t][1] < tau) + (v[t][2] < tau) + (v[t][3] < tau);
        }
        for (int off = 32; off; off >>= 1) lc += __shfl_xor(lc, off, 64);
        if (lc >= TOPK && lc <= CAP) break;
        if (lc < TOPK) lo = tau; else hi = tau;
        tau = 0.5f * (lo + hi);
    }

    int cnt = 0;
#pragma unroll
    for (int t = 0; t < 16; t++) {
#pragma unroll
        for (int c = 0; c < 4; c++) {
            float x = v[t][c];
            bool p = x < tau;
            unsigned long long mk = __ballot(p);
            if (p) {
                int pos = cnt + __popcll(mk & ((1ull << lane) - 1ull));
                if (pos < CAP) {
                    cbv[wave][pos] = x;
                    cbi[wave][pos] = (t * 64 + lane) * 4 + c;
                }
            }
            cnt += __popcll(mk);
        }
    }
    if (cnt > CAP) cnt = CAP;

    float mv[3]; int mi[3];
#pragma unroll
    for (int r = 0; r < 3; r++) {
        int p = r * 64 + lane;
        bool ok = p < cnt;
        mv[r] = ok ? cbv[wave][p] : INFINITY;
        mi[r] = ok ? cbi[wave][p] : 0x7FFFFFFF;
    }

    for (int t = 0; t < TOPK; t++) {
        float bv = mv[0]; int bi = mi[0];
        if (mv[1] < bv || (mv[1] == bv && mi[1] < bi)) { bv = mv[1]; bi = mi[1]; }
        if (mv[2] < bv || (mv[2] == bv && mi[2] < bi)) { bv = mv[2]; bi = mi[2]; }
        for (int off = 32; off; off >>= 1) {
            float ov = __shfl_xor(bv, off, 64);
            int   oi = __shfl_xor(bi, off, 64);
            if (ov < bv || (ov == bv && oi < bi)) { bv = ov; bi = oi; }
        }
        if (lane == 0) {
            stv[wave][t] = bv;
            sti[wave][t] = (bi >= 0 && bi < NROWS) ? bi : 0;
        }
#pragma unroll
        for (int r = 0; r < 3; r++)
            if (mi[r] == bi) { mv[r] = INFINITY; mi[r] = 0x7FFFFFFF; }
    }
    // wave-private LDS: lane0's writes ordered before this wave's reads (R2-proven)

    // ---- phase 2: triplet logic for row `row` (wave-uniform) ----
    int i = row;
    float thr = *thr_p;
    int c = tgt[i];
    int cc = class_cnt[c];
    const int* mem = class_mem + c * MAXM;

    int pos_i = 0;
    for (int k = 0; k < cc; k++) { if (mem[k] == i) { pos_i = k; break; } }

    int rp = 0;
    if (cc > 1) {
        uint32_t r = rnd_u32((uint32_t)i, 0x9111u) % (uint32_t)(cc - 1);
        if ((int)r >= pos_i) r++;
        rp = mem[r];
    }

    int hn = sti[wave][0];
    float an0 = sqrtf(fmaxf(stv[wave][0], 1e-12f));
    bool p_neg = prob[hn] >= thr;
    bool is_FN = (pred_cls[hn] == c);

    int sel = 11;
    for (int k = 1; k <= 11; k++) {
        int cd = sti[wave][k];
        if (prob[cd] >= thr) { sel = k; break; }
    }
    float anB = sqrtf(fmaxf(stv[wave][sel], 1e-12f));

    int first_valid = -1, last_draw = 0;
    for (int k = 0; k < 6; k++) {
        uint32_t r = rnd_u32((uint32_t)i, 0xD000u + (uint32_t)k) % (uint32_t)(cc > 0 ? cc : 1);
        int dk = mem[r];
        last_draw = dk;
        if (first_valid < 0 && dk != i && prob[dk] >= thr) first_valid = dk;
    }
    int rp_new = (first_valid >= 0) ? first_valid : last_draw;
    bool p_pos = prob[rp] >= thr;

    const f16x8* xi = (const f16x8*)(Xh + (size_t)i * DIM);
    const f16x8* xr = (const f16x8*)(Xh + (size_t)rp * DIM);
    const f16x8* xn = (const f16x8*)(Xh + (size_t)rp_new * DIM);
    float s1 = 0.f, s2 = 0.f;
    for (int k = lane; k < DIM / 8; k += 64) {
        f16x8 a = xi[k], b2 = xr[k], d2 = xn[k];
#pragma unroll
        for (int e = 0; e < 8; e++) {
            float ax = (float)a[e];
            s1 += ax * (float)b2[e];
            s2 += ax * (float)d2[e];
        }
    }
    for (int off = 32; off; off >>= 1) {
        s1 += __shfl_xor(s1, off, 64);
        s2 += __shfl_xor(s2, off, 64);
    }
    if (lane == 0) {
        float ap0 = sqrtf(fmaxf(sq[i] + sq[rp]     - 2.f * s1, 1e-12f));
        float apC = sqrtf(fmaxf(sq[i] + sq[rp_new] - 2.f * s2, 1e-12f));
        float apB = (ap0 + an0) * 0.5f;
        float anC = (ap0 + an0) * 0.5f;
        bool useB = p_pos && !p_neg && is_FN;
        bool useC = (!p_pos && p_neg) || (!p_pos && !p_neg && !is_FN);
        bool inverse = !p_pos && !p_neg && is_FN;
        float ap = useB ? apB : (useC ? apC : ap0);
        float an = useB ? anB : (useC ? anC : an0);
        float pl = inverse ? fmaxf(an - ap + MARGIN_F, 0.f)
                           : fmaxf(ap - an + MARGIN_F, 0.f);
        bool conf = prob[i] >= thr;
        row_loss[i] = conf ? pl : 0.f;
        row_corr[i] = (conf && (an >= ap)) ? 1 : 0;
    }
}

// ---------- fallback path (proven R1): fused fp32 GEMM + per-row top-12 ----------
__launch_bounds__(256)
__global__ void dist_topk_kernel(const float* __restrict__ X, const float* __restrict__ sq,
                                 const int* __restrict__ tgt,
                                 float* __restrict__ part_v, int* __restrict__ part_i) {
    __shared__ float As[BK][BM];
    __shared__ float Bs[BK][BN];
    __shared__ float Cs[BM][BN + 1];
    __shared__ float sqA[BM], sqB[BN];
    __shared__ int   tgA[BM], tgB[BN];

    int rowBase = blockIdx.x * BM;
    int slice = blockIdx.y;
    int tid = threadIdx.x;
    int tx = tid & 15, ty = tid >> 4;

    if (tid < BM) { sqA[tid] = sq[rowBase + tid]; tgA[tid] = tgt[rowBase + tid]; }

    float lv[TOPK]; int li[TOPK];
#pragma unroll
    for (int k = 0; k < TOPK; k++) { lv[k] = INFINITY; li[k] = -1; }

    for (int jt = 0; jt < COLS_PER_SLICE / BN; jt++) {
        int colBase = slice * COLS_PER_SLICE + jt * BN;
        __syncthreads();
        if (tid < BN) { sqB[tid] = sq[colBase + tid]; tgB[tid] = tgt[colBase + tid]; }

        float acc[4][4] = {};
        for (int kb = 0; kb < DIM; kb += BK) {
            int r  = tid >> 2;
            int kk = (tid & 3) * 4;
            float4 va = *(const float4*)(X + (size_t)(rowBase + r) * DIM + kb + kk);
            As[kk + 0][r] = va.x; As[kk + 1][r] = va.y; As[kk + 2][r] = va.z; As[kk + 3][r] = va.w;
            float4 vb = *(const float4*)(X + (size_t)(colBase + r) * DIM + kb + kk);
            Bs[kk + 0][r] = vb.x; Bs[kk + 1][r] = vb.y; Bs[kk + 2][r] = vb.z; Bs[kk + 3][r] = vb.w;
            __syncthreads();
#pragma unroll
            for (int k = 0; k < BK; k++) {
                float a[4], b2[4];
                *(float4*)a = *(const float4*)&As[k][ty * 4];
                *(float4*)b2 = *(const float4*)&Bs[k][tx * 4];
#pragma unroll
                for (int i2 = 0; i2 < 4; i2++)
#pragma unroll
                    for (int j2 = 0; j2 < 4; j2++)
                        acc[i2][j2] += a[i2] * b2[j2];
            }
            __syncthreads();
        }
#pragma unroll
        for (int i2 = 0; i2 < 4; i2++) {
            int r = ty * 4 + i2;
#pragma unroll
            for (int j2 = 0; j2 < 4; j2++) {
                int c = tx * 4 + j2;
                float d2 = sqA[r] + sqB[c] - 2.f * acc[i2][j2];
                if (tgA[r] == tgB[c]) d2 = INFINITY;
                Cs[r][c] = d2;
            }
        }
        __syncthreads();
        if (tid < BM) {
            int r = tid;
            for (int c = 0; c < BN; c++) {
                float v = Cs[r][c];
                if (v < lv[TOPK - 1]) {
                    float nv = v; int ni = colBase + c;
#pragma unroll
                    for (int p = 0; p < TOPK; p++) {
                        if (nv < lv[p]) {
                            float tv = lv[p]; int ti = li[p];
                            lv[p] = nv; li[p] = ni;
                            nv = tv; ni = ti;
                        }
                    }
                }
            }
        }
    }
    if (tid < BM) {
        int r = tid;
#pragma unroll
        for (int k = 0; k < TOPK; k++) {
            size_t o = ((size_t)(rowBase + r) * SLICES + slice) * TOPK + k;
            part_v[o] = lv[k];
            part_i[o] = li[k];
        }
    }
}

__global__ void topk_merge_kernel(const float* __restrict__ part_v, const int* __restrict__ part_i,
                                  float* __restrict__ top_v, int* __restrict__ top_i) {
    int row = blockIdx.x * blockDim.x + threadIdx.x;
    if (row >= NROWS) return;
    float lv[TOPK]; int li[TOPK];
#pragma unroll
    for (int k = 0; k < TOPK; k++) { lv[k] = INFINITY; li[k] = -1; }
    for (int s = 0; s < SLICES; s++) {
        for (int k = 0; k < TOPK; k++) {
            size_t o = ((size_t)row * SLICES + s) * TOPK + k;
            float v = part_v[o];
            if (!(v < lv[TOPK - 1])) break;
            int idx = part_i[o];
            float nv = v; int ni = idx;
#pragma unroll
            for (int p = 0; p < TOPK; p++) {
                if (nv < lv[p]) {
                    float tv = lv[p]; int ti = li[p];
                    lv[p] = nv; li[p] = ni;
                    nv = tv; ni = ti;
                }
            }
        }
    }
#pragma unroll
    for (int k = 0; k < TOPK; k++) {
        top_v[(size_t)row * TOPK + k] = lv[k];
        top_i[(size_t)row * TOPK + k] = li[k];
    }
}

// fallback rowlogic on fp32 X
__global__ void rowlogic_f32_kernel(const float* __restrict__ X, const float* __restrict__ sq,
                                    const float* __restrict__ prob, const float* __restrict__ thr_p,
                                    const int* __restrict__ tgt, const int* __restrict__ pred_cls,
                                    const int* __restrict__ class_cnt, const int* __restrict__ class_mem,
                                    const float* __restrict__ top_v, const int* __restrict__ top_i,
                                    float* __restrict__ row_loss, int* __restrict__ row_corr) {
    int i = (blockIdx.x * blockDim.x + threadIdx.x) >> 6;
    int lane = threadIdx.x & 63;
    if (i >= NROWS) return;
    float thr = *thr_p;

    int c = tgt[i];
    int cc = class_cnt[c];
    const int* mem = class_mem + c * MAXM;

    int pos_i = 0;
    for (int k = 0; k < cc; k++) { if (mem[k] == i) { pos_i = k; break; } }

    int rp = 0;
    if (cc > 1) {
        uint32_t r = rnd_u32((uint32_t)i, 0x9111u) % (uint32_t)(cc - 1);
        if ((int)r >= pos_i) r++;
        rp = mem[r];
    }

    int hn = top_i[(size_t)i * TOPK + 0];
    float an0 = sqrtf(fmaxf(top_v[(size_t)i * TOPK + 0], 1e-12f));
    bool p_neg = prob[hn] >= thr;
    bool is_FN = (pred_cls[hn] == c);

    int sel = 11;
    for (int k = 1; k <= 11; k++) {
        int cd = top_i[(size_t)i * TOPK + k];
        if (prob[cd] >= thr) { sel = k; break; }
    }
    float anB = sqrtf(fmaxf(top_v[(size_t)i * TOPK + sel], 1e-12f));

    int first_valid = -1, last_draw = 0;
    for (int k = 0; k < 6; k++) {
        uint32_t r = rnd_u32((uint32_t)i, 0xD000u + (uint32_t)k) % (uint32_t)(cc > 0 ? cc : 1);
        int dk = mem[r];
        last_draw = dk;
        if (first_valid < 0 && dk != i && prob[dk] >= thr) first_valid = dk;
    }
    int rp_new = (first_valid >= 0) ? first_valid : last_draw;
    bool p_pos = prob[rp] >= thr;

    const float4* xi = (const float4*)(X + (size_t)i * DIM);
    const float4* xr = (const float4*)(X + (size_t)rp * DIM);
    const float4* xn = (const float4*)(X + (size_t)rp_new * DIM);
    float s1 = 0.f, s2 = 0.f;
    for (int k = lane; k < DIM / 4; k += 64) {
        float4 a = xi[k], b = xr[k], d = xn[k];
        s1 += a.x * b.x + a.y * b.y + a.z * b.z + a.w * b.w;
        s2 += a.x * d.x + a.y * d.y + a.z * d.z + a.w * d.w;
    }
    for (int off = 32; off; off >>= 1) {
        s1 += __shfl_xor(s1, off, 64);
        s2 += __shfl_xor(s2, off, 64);
    }
    if (lane == 0) {
        float ap0 = sqrtf(fmaxf(sq[i] + sq[rp]     - 2.f * s1, 1e-12f));
        float apC = sqrtf(fmaxf(sq[i] + sq[rp_new] - 2.f * s2, 1e-12f));
        float apB = (ap0 + an0) * 0.5f;
        float anC = (ap0 + an0) * 0.5f;
        bool useB = p_pos && !p_neg && is_FN;
        bool useC = (!p_pos && p_neg) || (!p_pos && !p_neg && !is_FN);
        bool inverse = !p_pos && !p_neg && is_FN;
        float ap = useB ? apB : (useC ? apC : ap0);
        float an = useB ? anB : (useC ? anC : an0);
        float pl = inverse ? fmaxf(an - ap + MARGIN_F, 0.f)
                           : fmaxf(ap - an + MARGIN_F, 0.f);
        bool conf = prob[i] >= thr;
        row_loss[i] = conf ? pl : 0.f;
        row_corr[i] = (conf && (an >= ap)) ? 1 : 0;
    }
}

// ---------- final reduction ----------
__global__ void reduce_kernel(const float* __restrict__ row_loss, const int* __restrict__ row_corr,
                              const float* __restrict__ prob, const float* __restrict__ thr_p,
                              float* __restrict__ out) {
    __shared__ float sl[256];
    __shared__ int   sc[256];
    __shared__ int   sn[256];
    float thr = *thr_p;
    int tid = threadIdx.x;
    float l = 0.f; int corr = 0, cnt = 0;
    for (int i = tid; i < NROWS; i += 256) {
        l += row_loss[i];
        corr += row_corr[i];
        cnt += (prob[i] >= thr) ? 1 : 0;
    }
    sl[tid] = l; sc[tid] = corr; sn[tid] = cnt;
    __syncthreads();
    for (int off = 128; off; off >>= 1) {
        if (tid < off) {
            sl[tid] += sl[tid + off];
            sc[tid] += sc[tid + off];
            sn[tid] += sn[tid + off];
        }
        __syncthreads();
    }
    if (tid == 0) {
        int cn = sn[0];
        float loss = (cn > 0) ? (sl[0] / (float)(cn > 1 ? cn : 1)) : 0.f;
        out[0] = loss;
        out[1] = (float)sc[0];
        out[2] = (float)cn;
    }
}

extern "C" void kernel_launch(void* const* d_in, const int* in_sizes, int n_in,
                              void* d_out, int out_size, void* d_ws, size_t ws_size,
                              hipStream_t stream) {
    const float* X    = (const float*)d_in[0];
    const float* P    = (const float*)d_in[1];
    const int*   tgt  = (const int*)d_in[2];
    const float* prob = (const float*)d_in[4];
    const float* thr  = (const float*)d_in[5];
    float* out = (float*)d_out;

    char* w = (char*)d_ws;
    auto alloc = [&](size_t bytes) {
        char* p = w;
        w += (bytes + 255) & ~(size_t)255;
        return p;
    };
    float* sq        = (float*)alloc(NROWS * sizeof(float));
    int*   pred_cls  = (int*)  alloc(NROWS * sizeof(int));
    int*   class_cnt = (int*)  alloc(CNUM * sizeof(int));
    int*   class_mem = (int*)  alloc((size_t)CNUM * MAXM * sizeof(int));
    float* top_v     = (float*)alloc((size_t)NROWS * TOPK * sizeof(float));
    int*   top_i     = (int*)  alloc((size_t)NROWS * TOPK * sizeof(int));
    float* row_loss  = (float*)alloc(NROWS * sizeof(float));
    int*   row_corr  = (int*)  alloc(NROWS * sizeof(int));
    char*  var_base  = w;

    // fast path: Xh (16.8 MB) + fp32 dist (64 MB)
    size_t fast_need = (size_t)NROWS * DIM * 2 + (size_t)NROWS * NROWS * 4 + (1 << 20);
    bool fast = ((size_t)(var_base - (char*)d_ws) + fast_need) <= ws_size;

    if (fast) {
        _Float16* Xh   = (_Float16*)alloc((size_t)NROWS * DIM * 2);
        float*    dist = (float*)alloc((size_t)NROWS * NROWS * 4);
        setup_kernel<<<NROWS + NROWS / 4 + CNUM / 4, 256, 0, stream>>>(
            X, Xh, sq, P, pred_cls, tgt, class_cnt, class_mem);
        mfma_dist_kernel<<<528, 256, 0, stream>>>(Xh, sq, tgt, dist);
        topk_logic_kernel<<<NROWS / 4, 256, 0, stream>>>(dist, Xh, sq, prob, thr, tgt, pred_cls,
                                                         class_cnt, class_mem,
                                                         row_loss, row_corr);
    } else {
        rowsq_kernel<<<NROWS / 4, 256, 0, stream>>>(X, sq);
        predcls_kernel<<<NROWS / 4, 256, 0, stream>>>(P, pred_cls);
        classlist_kernel<<<CNUM / 4, 256, 0, stream>>>(tgt, class_cnt, class_mem);
        float* part_v = (float*)alloc((size_t)NROWS * SLICES * TOPK * sizeof(float));
        int*   part_i = (int*)  alloc((size_t)NROWS * SLICES * TOPK * sizeof(int));
        dist_topk_kernel<<<dim3(NROWS / BM, SLICES), 256, 0, stream>>>(X, sq, tgt, part_v, part_i);
        topk_merge_kernel<<<NROWS / 256, 256, 0, stream>>>(part_v, part_i, top_v, top_i);
        rowlogic_f32_kernel<<<NROWS / 4, 256, 0, stream>>>(X, sq, prob, thr, tgt, pred_cls,
                                                           class_cnt, class_mem, top_v, top_i,
                                                           row_loss, row_corr);
    }

    reduce_kernel<<<1, 256, 0, stream>>>(row_loss, row_corr, prob, thr, out);
}